// Round 20
// baseline (157.383 us; speedup 1.0000x reference)
//
#include <hip/hip_runtime.h>

typedef short short8 __attribute__((ext_vector_type(8)));
typedef float f32x4 __attribute__((ext_vector_type(4)));

#define NROWS 65536        // B*T = 32*2048
#define NCOMPACT 640       // compacted+padded OUT columns

__device__ __forceinline__ short f2bf(float f) {
  union { float f; unsigned u; } c; c.f = f;
  unsigned r = (c.u + 0x7fffu + ((c.u >> 16) & 1u)) >> 16;
  return (short)r;
}

__device__ __forceinline__ float fastrcp(float a) {
  float r; asm("v_rcp_f32 %0, %1" : "=v"(r) : "v"(a)); return r;
}

// Map compacted column n -> original W3/b3 column (or -1 for zero pad).
__device__ __forceinline__ int w3col(int n) {
  if (n < 32)  return 32 + n;
  if (n < 64)  return 96 + (n - 32);
  if (n < 72)  return 128 + (n - 64);
  if (n < 96)  return -1;
  if (n < 352) { int q = n - 96;  return 168 + (q >> 5) * 64 + (q & 31); }
  if (n < 608) { int q = n - 352; return 680 + (q >> 5) * 64 + (q & 31); }
  return -1;
}

__global__ __launch_bounds__(256) void prep_w_kernel(
    const float* __restrict__ W1, const float* __restrict__ W2,
    const float* __restrict__ W3, const float* __restrict__ b3,
    short* __restrict__ w1t, short* __restrict__ w2t,
    short* __restrict__ w3t, float* __restrict__ b3c) {
  const int NW1 = 512 * 32, NW2 = 512 * 512, NW3 = NCOMPACT * 512;
  int t = blockIdx.x * 256 + threadIdx.x;
  if (t < NW1) {
    int n = t >> 5, k = t & 31;
    w1t[t] = f2bf(W1[k * 512 + n]);
  } else if (t < NW1 + NW2) {
    int i = t - NW1; int n = i >> 9, k = i & 511;
    w2t[i] = f2bf(W2[k * 512 + n]);
  } else if (t < NW1 + NW2 + NW3) {
    int i = t - NW1 - NW2; int n = i >> 9, k = i & 511;
    int c = w3col(n);
    w3t[i] = (c >= 0) ? f2bf(W3[(size_t)k * 1160 + c]) : (short)0;
  } else if (t < NW1 + NW2 + NW3 + NCOMPACT) {
    int n = t - NW1 - NW2 - NW3;
    int c = w3col(n);
    b3c[n] = (c >= 0) ? b3[c] : 0.0f;
  }
}

// Fused G1+G2: h2 = relu(relu(x[:,:32]@W1^T + b1)@W2^T + b2). Block 128x128,
// 4 waves, BK=32, 16 K-steps. h1 never exists in HBM. R13-exact structure +
// __launch_bounds__(256, 4): forcing combined regs <=128 doubles resident waves.
#define ASTR 40
__global__ __launch_bounds__(256, 4) void g12_kernel(
    const float* __restrict__ x,      // fp32 [NROWS][64]
    const short* __restrict__ w1t,    // bf16 [512][32]
    const float* __restrict__ b1,     // fp32 [512]
    const short* __restrict__ w2t,    // bf16 [512][512]
    const float* __restrict__ b2,     // fp32 [512]
    short* __restrict__ h2) {         // bf16 [NROWS][512]
  __shared__ __attribute__((aligned(16))) short As[128 * ASTR];
  __shared__ __attribute__((aligned(16))) short Bs[2][128 * 32];
  __shared__ __attribute__((aligned(16))) short W1b[2][32 * 32];
  const int tid = threadIdx.x;
  const int cpx = gridDim.x >> 3;
  const int s = blockIdx.x;
  const int w = (s & 7) * cpx + (s >> 3);       // XCD-contiguous work id
  const int m0 = (w >> 2) * 128, n0 = (w & 3) * 128;
  const int lane = tid & 63, wid = tid >> 6;
  const int wm = (wid >> 1) * 64, wn = (wid & 1) * 64;
  const int lr = lane & 15, hi = lane >> 4, lk = hi * 8;

  // held xc fragments: block-local rows wid*32 + mi*16 + lr, k = lk..lk+8
  short8 xcf[2];
#pragma unroll
  for (int mi = 0; mi < 2; ++mi) {
    int row = m0 + wid * 32 + mi * 16 + lr;
    const float* xs = x + (size_t)row * 64 + lk;
    f32x4 v0 = *(const f32x4*)xs;
    f32x4 v1 = *(const f32x4*)(xs + 4);
    short8 v;
#pragma unroll
    for (int i = 0; i < 4; ++i) { v[i] = f2bf(v0[i]); v[4 + i] = f2bf(v1[i]); }
    xcf[mi] = v;
  }

  auto STAGE_B = [&](int buf, int kt) {
#pragma unroll
    for (int base = wid * 64; base < 512; base += 256) {
      int c = base + lane;
      int row = c >> 2;
      int skb = ((c & 3) ^ ((row >> 1) & 3)) << 4;
      const char* g = (const char*)(w2t + (size_t)(n0 + row) * 512 + kt) + skb;
      __builtin_amdgcn_global_load_lds(
          (const __attribute__((address_space(1))) void*)g,
          (__attribute__((address_space(3))) void*)((char*)Bs[buf] + base * 16),
          16, 0, 0);
    }
  };
  auto STAGE_W1 = [&](int buf, int kt) {
    if (wid < 2) {
      int c = wid * 64 + lane;
      int row = c >> 2;
      int skb = ((c & 3) ^ ((row >> 1) & 3)) << 4;
      const char* g = (const char*)(w1t + (size_t)(kt + row) * 32) + skb;
      __builtin_amdgcn_global_load_lds(
          (const __attribute__((address_space(1))) void*)g,
          (__attribute__((address_space(3))) void*)((char*)W1b[buf] + wid * 1024),
          16, 0, 0);
    }
  };

  // compute h1 chunk quarter (rows wid*32..+32, k-cols kt..kt+32) -> As (padded)
  auto H1STEP = [&](int buf, int kt) {
    const short* Wb = W1b[buf];
    short8 wf[2];
#pragma unroll
    for (int ni = 0; ni < 2; ++ni) {
      int row = ni * 16 + lr;
      wf[ni] = *(const short8*)(&Wb[row * 32 + (lk ^ (((row >> 1) & 3) << 3))]);
    }
    f32x4 a1[2][2] = {};
#pragma unroll
    for (int mi = 0; mi < 2; ++mi)
#pragma unroll
      for (int ni = 0; ni < 2; ++ni)
        a1[mi][ni] = __builtin_amdgcn_mfma_f32_16x16x32_bf16(
            xcf[mi], wf[ni], a1[mi][ni], 0, 0, 0);
#pragma unroll
    for (int ni = 0; ni < 2; ++ni) {
      int acol = ni * 16 + lr;
      float bv = b1[kt + acol];
#pragma unroll
      for (int mi = 0; mi < 2; ++mi)
#pragma unroll
        for (int j = 0; j < 4; ++j) {
          int arow = wid * 32 + mi * 16 + hi * 4 + j;
          As[arow * ASTR + acol] = f2bf(fmaxf(a1[mi][ni][j] + bv, 0.0f));
        }
    }
  };

  f32x4 acc[4][4] = {};
  auto COMPUTE = [&](int buf) {
    short8 af[4], bf_[4];
#pragma unroll
    for (int mi = 0; mi < 4; ++mi) {
      int row = wm + mi * 16 + lr;
      af[mi] = *(const short8*)(&As[row * ASTR + lk]);
    }
#pragma unroll
    for (int ni = 0; ni < 4; ++ni) {
      int row = wn + ni * 16 + lr;
      bf_[ni] = *(const short8*)(&Bs[buf][row * 32 + (lk ^ (((row >> 1) & 3) << 3))]);
    }
#pragma unroll
    for (int mi = 0; mi < 4; ++mi)
#pragma unroll
      for (int ni = 0; ni < 4; ++ni)
        acc[mi][ni] = __builtin_amdgcn_mfma_f32_16x16x32_bf16(
            af[mi], bf_[ni], acc[mi][ni], 0, 0, 0);
  };

  STAGE_B(0, 0); STAGE_W1(0, 0);
  __syncthreads();
  for (int t = 0; t < 16; ++t) {
    int pb = t & 1;
    if (t < 15) { STAGE_B(pb ^ 1, (t + 1) * 32); STAGE_W1(pb ^ 1, (t + 1) * 32); }
    H1STEP(pb, t * 32);
    __syncthreads();       // h1 chunk visible (also drains staged loads)
    COMPUTE(pb);
    __syncthreads();       // As/Bs reads done -> next overwrite safe
  }

  // epilogue: h2 = relu(acc + b2) -> bf16
#pragma unroll
  for (int ni = 0; ni < 4; ++ni) {
    int col = n0 + wn + ni * 16 + lr;
    float bv = b2[col];
#pragma unroll
    for (int mi = 0; mi < 4; ++mi) {
#pragma unroll
      for (int j = 0; j < 4; ++j) {
        int row = m0 + wm + mi * 16 + hi * 4 + j;
        h2[(size_t)row * 512 + col] = f2bf(fmaxf(acc[mi][ni][j] + bv, 0.0f));
      }
    }
  }
}

// GEMM3 + mixture-CDF transform, fused — SINGLE-BUFFERED variant for 2 blocks/CU.
// Block = 128 rows x 640 cols, 16 waves (4Mx4N), wave = 32 rows x 160 cols ->
// acc[2][10] = 80 regs (identical COMPUTE/addressing/swizzle to champion).
// One 48KB K-tile buffer (A 8KB + B 40KB): stage -> sync(A: vmcnt drained) ->
// compute -> sync(B: reads done) per K-step. 2 blocks (32 waves = CU max)
// resident: each block's stage stall hides under the other's compute (m97
// mechanism). Traffic identical to champion (FETCH ~46MB). Epilogue: eight
// 16-row phases through plds [16][644] f32 (41KB, fits the 48KB footprint).
#define PSTR 644
__global__ __launch_bounds__(1024, 4) void gemm3_fused_kernel(
    const short* __restrict__ A,      // h2 bf16 [NROWS][512]
    const short* __restrict__ Bw,     // w3t bf16 [640][512]
    const float* __restrict__ b3c,    // [640]
    const float* __restrict__ x,      // fp32 [NROWS][64]
    float* __restrict__ out) {
  __shared__ __attribute__((aligned(16))) char lds[49152];
  const int tid = threadIdx.x;
  const int m0 = blockIdx.x * 128;
  const int lane = tid & 63, wid = tid >> 6;   // wid 0..15
  const int wr = wid >> 2, wc = wid & 3;       // wr: 32-row group, wc: 160-col group
  const int lr = lane & 15, hi = lane >> 4, lk = hi * 8;

  f32x4 acc[2][10] = {};

  auto STAGE = [&](int kt) {
#pragma unroll
    for (int base = wid * 64; base < 3072; base += 1024) {
      int c = base + lane;
      char* dst = lds + (size_t)base * 16;        // HW adds lane*16
      if (base < 512) {                           // A chunks [0,512)
        int row = c >> 2;
        int skb = ((c & 3) ^ ((row >> 1) & 3)) << 4;
        const char* ga = (const char*)(A + (size_t)(m0 + row) * 512 + kt) + skb;
        __builtin_amdgcn_global_load_lds(
            (const __attribute__((address_space(1))) void*)ga,
            (__attribute__((address_space(3))) void*)dst, 16, 0, 0);
      } else {                                    // B chunks [512,3072)
        int q = c - 512;
        int row = q >> 2;
        int skb = ((q & 3) ^ ((row >> 1) & 3)) << 4;
        const char* gb = (const char*)(Bw + (size_t)row * 512 + kt) + skb;
        __builtin_amdgcn_global_load_lds(
            (const __attribute__((address_space(1))) void*)gb,
            (__attribute__((address_space(3))) void*)dst, 16, 0, 0);
      }
    }
  };

  auto COMPUTE = [&]() {
    const short* As = (const short*)lds;
    const short* Bs = (const short*)(lds + 8192);
    short8 af[2];
#pragma unroll
    for (int mi = 0; mi < 2; ++mi) {
      int row = wr * 32 + mi * 16 + lr;
      int k = lk ^ (((row >> 1) & 3) << 3);
      af[mi] = *(const short8*)(&As[row * 32 + k]);
    }
#pragma unroll
    for (int ni = 0; ni < 10; ++ni) {
      int brow = wc * 160 + ni * 16 + lr;
      int k = lk ^ (((brow >> 1) & 3) << 3);
      short8 bf_ = *(const short8*)(&Bs[brow * 32 + k]);
      acc[0][ni] = __builtin_amdgcn_mfma_f32_16x16x32_bf16(af[0], bf_, acc[0][ni], 0, 0, 0);
      acc[1][ni] = __builtin_amdgcn_mfma_f32_16x16x32_bf16(af[1], bf_, acc[1][ni], 0, 0, 0);
    }
  };

  for (int t = 0; t < 16; ++t) {
    STAGE(t * 32);
    __syncthreads();       // stage complete (vmcnt drained before barrier)
    COMPUTE();
    __syncthreads();       // all reads done -> next stage may overwrite
  }

  // ---- fused transform epilogue: eight 16-row phases ----
  float* plds = (float*)lds;                 // [16][PSTR] f32 = 41216 B
  float* xo  = out;
  float* ldo = out + (size_t)NROWS * 64;
#pragma unroll
  for (int p = 0; p < 8; ++p) {
    if (p) __syncthreads();
    if (wr == (p >> 1)) {
      int mi = p & 1;                        // compile-time (unrolled)
#pragma unroll
      for (int ni = 0; ni < 10; ++ni) {
        int col = wc * 160 + ni * 16 + lr;
        float bv = b3c[col];
#pragma unroll
        for (int j = 0; j < 4; ++j)
          plds[(hi * 4 + j) * PSTR + col] = acc[mi][ni][j] + bv;
      }
    }
    __syncthreads();
    if (tid < 512) {
      int rl = tid >> 5, j = tid & 31;       // rl 0..15, j 0..31
      const float* p_ = plds + rl * PSTR;
      int grow = m0 + p * 16 + rl;

      float lg[8];
#pragma unroll
      for (int k = 0; k < 8; ++k) lg[k] = p_[64 + k];
      float mx = lg[0];
#pragma unroll
      for (int k = 1; k < 8; ++k) mx = fmaxf(mx, lg[k]);
      float wgt[8], wsum = 0.0f;
#pragma unroll
      for (int k = 0; k < 8; ++k) { wgt[k] = __expf(lg[k] - mx); wsum += wgt[k]; }

      float xd = x[(size_t)grow * 64 + 32 + j];
      float zs = 0.0f, ps = 0.0f;
#pragma unroll
      for (int k = 0; k < 8; ++k) {
        float mu   = p_[96 + k * 32 + j];
        float lstd = p_[352 + k * 32 + j];
        float istd = __expf(-lstd);
        float u = (xd - mu) * istd;
        float x2 = 0.5f * u * u;                 // = (u/sqrt2)^2
        float e  = __expf(-x2);                  // e^{-u^2/2}
        ps += wgt[k] * e * istd;
        // 0.5*erfc(|u|/sqrt2), NR rational approx (rel err < 1.2e-7), shares x2:
        float ax = fabsf(u) * 0.70710678118654752f;
        float t_ = fastrcp(fmaf(0.5f, ax, 1.0f));
        float poly = -1.26551223f + t_*(1.00002368f + t_*(0.37409196f +
                     t_*(0.09678418f + t_*(-0.18628806f + t_*(0.27886807f +
                     t_*(-1.13520398f + t_*(1.48851587f + t_*(-0.82215223f +
                     t_*0.17087277f))))))));
        float erfc_half = 0.5f * t_ * __expf(poly - x2);
        float cdf = (u >= 0.0f) ? 1.0f - erfc_half : erfc_half;
        zs += wgt[k] * cdf;
      }
      float winv = fastrcp(wsum);
      float z  = zs * winv;
      float pm = ps * winv * 0.39894228040143268f;
      float logz = __logf(z), log1mz = __logf(1.0f - z);
      float ls = p_[j], bv = p_[32 + j];
      float outv = (logz - log1mz) * __expf(ls) + bv;
      float ld = __logf(pm) - logz - log1mz + ls;

      size_t base = (size_t)grow * 64;
      xo[base + j]       = x[base + j];
      xo[base + 32 + j]  = outv;
      ldo[base + j]      = 0.0f;
      ldo[base + 32 + j] = ld;
    }
  }
}

extern "C" void kernel_launch(void* const* d_in, const int* in_sizes, int n_in,
                              void* d_out, int out_size, void* d_ws, size_t ws_size,
                              hipStream_t stream) {
  const float* x  = (const float*)d_in[0];
  const float* W1 = (const float*)d_in[1];
  const float* b1 = (const float*)d_in[2];
  const float* W2 = (const float*)d_in[3];
  const float* b2 = (const float*)d_in[4];
  const float* W3 = (const float*)d_in[5];
  const float* b3 = (const float*)d_in[6];
  char* ws = (char*)d_ws;

  short* h2  = (short*)ws;                          // 64 MB  bf16 [65536][512]
  short* w1t = (short*)(ws + 67108864);             // 32 KB  bf16 [512][32]
  short* w2t = (short*)(ws + 67141632);             // 512 KB bf16 [512][512]
  short* w3t = (short*)(ws + 67665920);             // 640 KB bf16 [640][512]
  float* b3c = (float*)(ws + 68321280);             // 2.5 KB fp32 [640]
  float* out = (float*)d_out;

  {
    int total = 512 * 32 + 512 * 512 + NCOMPACT * 512 + NCOMPACT;
    prep_w_kernel<<<(total + 255) / 256, 256, 0, stream>>>(W1, W2, W3, b3, w1t, w2t, w3t, b3c);
  }
  g12_kernel<<<2048, 256, 0, stream>>>(x, w1t, b1, w2t, b2, h2);
  gemm3_fused_kernel<<<NROWS / 128, 1024, 0, stream>>>(h2, w3t, b3c, x, out);
}

// Round 21
// 133.426 us; speedup vs baseline: 1.1795x; 1.1795x over previous
//
#include <hip/hip_runtime.h>

typedef short short8 __attribute__((ext_vector_type(8)));
typedef float f32x4 __attribute__((ext_vector_type(4)));

#define NROWS 65536        // B*T = 32*2048
#define NCOMPACT 640       // compacted+padded OUT columns

__device__ __forceinline__ short f2bf(float f) {
  union { float f; unsigned u; } c; c.f = f;
  unsigned r = (c.u + 0x7fffu + ((c.u >> 16) & 1u)) >> 16;
  return (short)r;
}

__device__ __forceinline__ float fastrcp(float a) {
  float r; asm("v_rcp_f32 %0, %1" : "=v"(r) : "v"(a)); return r;
}

// Map compacted column n -> original W3/b3 column (or -1 for zero pad).
__device__ __forceinline__ int w3col(int n) {
  if (n < 32)  return 32 + n;
  if (n < 64)  return 96 + (n - 32);
  if (n < 72)  return 128 + (n - 64);
  if (n < 96)  return -1;
  if (n < 352) { int q = n - 96;  return 168 + (q >> 5) * 64 + (q & 31); }
  if (n < 608) { int q = n - 352; return 680 + (q >> 5) * 64 + (q & 31); }
  return -1;
}

__global__ __launch_bounds__(256) void prep_w_kernel(
    const float* __restrict__ W1, const float* __restrict__ W2,
    const float* __restrict__ W3, const float* __restrict__ b3,
    short* __restrict__ w1t, short* __restrict__ w2t,
    short* __restrict__ w3t, float* __restrict__ b3c) {
  const int NW1 = 512 * 32, NW2 = 512 * 512, NW3 = NCOMPACT * 512;
  int t = blockIdx.x * 256 + threadIdx.x;
  if (t < NW1) {
    int n = t >> 5, k = t & 31;
    w1t[t] = f2bf(W1[k * 512 + n]);
  } else if (t < NW1 + NW2) {
    int i = t - NW1; int n = i >> 9, k = i & 511;
    w2t[i] = f2bf(W2[k * 512 + n]);
  } else if (t < NW1 + NW2 + NW3) {
    int i = t - NW1 - NW2; int n = i >> 9, k = i & 511;
    int c = w3col(n);
    w3t[i] = (c >= 0) ? f2bf(W3[(size_t)k * 1160 + c]) : (short)0;
  } else if (t < NW1 + NW2 + NW3 + NCOMPACT) {
    int n = t - NW1 - NW2 - NW3;
    int c = w3col(n);
    b3c[n] = (c >= 0) ? b3[c] : 0.0f;
  }
}

// Fused G1+G2: h2 = relu(relu(x[:,:32]@W1^T + b1)@W2^T + b2). Block 128x128,
// 4 waves, BK=32, 16 K-steps. h1 never exists in HBM. R13-exact structure +
// __launch_bounds__(256, 4): forcing combined regs <=128 doubles resident waves.
#define ASTR 40
__global__ __launch_bounds__(256, 4) void g12_kernel(
    const float* __restrict__ x,      // fp32 [NROWS][64]
    const short* __restrict__ w1t,    // bf16 [512][32]
    const float* __restrict__ b1,     // fp32 [512]
    const short* __restrict__ w2t,    // bf16 [512][512]
    const float* __restrict__ b2,     // fp32 [512]
    short* __restrict__ h2) {         // bf16 [NROWS][512]
  __shared__ __attribute__((aligned(16))) short As[128 * ASTR];
  __shared__ __attribute__((aligned(16))) short Bs[2][128 * 32];
  __shared__ __attribute__((aligned(16))) short W1b[2][32 * 32];
  const int tid = threadIdx.x;
  const int cpx = gridDim.x >> 3;
  const int s = blockIdx.x;
  const int w = (s & 7) * cpx + (s >> 3);       // XCD-contiguous work id
  const int m0 = (w >> 2) * 128, n0 = (w & 3) * 128;
  const int lane = tid & 63, wid = tid >> 6;
  const int wm = (wid >> 1) * 64, wn = (wid & 1) * 64;
  const int lr = lane & 15, hi = lane >> 4, lk = hi * 8;

  // held xc fragments: block-local rows wid*32 + mi*16 + lr, k = lk..lk+8
  short8 xcf[2];
#pragma unroll
  for (int mi = 0; mi < 2; ++mi) {
    int row = m0 + wid * 32 + mi * 16 + lr;
    const float* xs = x + (size_t)row * 64 + lk;
    f32x4 v0 = *(const f32x4*)xs;
    f32x4 v1 = *(const f32x4*)(xs + 4);
    short8 v;
#pragma unroll
    for (int i = 0; i < 4; ++i) { v[i] = f2bf(v0[i]); v[4 + i] = f2bf(v1[i]); }
    xcf[mi] = v;
  }

  auto STAGE_B = [&](int buf, int kt) {
#pragma unroll
    for (int base = wid * 64; base < 512; base += 256) {
      int c = base + lane;
      int row = c >> 2;
      int skb = ((c & 3) ^ ((row >> 1) & 3)) << 4;
      const char* g = (const char*)(w2t + (size_t)(n0 + row) * 512 + kt) + skb;
      __builtin_amdgcn_global_load_lds(
          (const __attribute__((address_space(1))) void*)g,
          (__attribute__((address_space(3))) void*)((char*)Bs[buf] + base * 16),
          16, 0, 0);
    }
  };
  auto STAGE_W1 = [&](int buf, int kt) {
    if (wid < 2) {
      int c = wid * 64 + lane;
      int row = c >> 2;
      int skb = ((c & 3) ^ ((row >> 1) & 3)) << 4;
      const char* g = (const char*)(w1t + (size_t)(kt + row) * 32) + skb;
      __builtin_amdgcn_global_load_lds(
          (const __attribute__((address_space(1))) void*)g,
          (__attribute__((address_space(3))) void*)((char*)W1b[buf] + wid * 1024),
          16, 0, 0);
    }
  };

  // compute h1 chunk quarter (rows wid*32..+32, k-cols kt..kt+32) -> As (padded)
  auto H1STEP = [&](int buf, int kt) {
    const short* Wb = W1b[buf];
    short8 wf[2];
#pragma unroll
    for (int ni = 0; ni < 2; ++ni) {
      int row = ni * 16 + lr;
      wf[ni] = *(const short8*)(&Wb[row * 32 + (lk ^ (((row >> 1) & 3) << 3))]);
    }
    f32x4 a1[2][2] = {};
#pragma unroll
    for (int mi = 0; mi < 2; ++mi)
#pragma unroll
      for (int ni = 0; ni < 2; ++ni)
        a1[mi][ni] = __builtin_amdgcn_mfma_f32_16x16x32_bf16(
            xcf[mi], wf[ni], a1[mi][ni], 0, 0, 0);
#pragma unroll
    for (int ni = 0; ni < 2; ++ni) {
      int acol = ni * 16 + lr;
      float bv = b1[kt + acol];
#pragma unroll
      for (int mi = 0; mi < 2; ++mi)
#pragma unroll
        for (int j = 0; j < 4; ++j) {
          int arow = wid * 32 + mi * 16 + hi * 4 + j;
          As[arow * ASTR + acol] = f2bf(fmaxf(a1[mi][ni][j] + bv, 0.0f));
        }
    }
  };

  f32x4 acc[4][4] = {};
  auto COMPUTE = [&](int buf) {
    short8 af[4], bf_[4];
#pragma unroll
    for (int mi = 0; mi < 4; ++mi) {
      int row = wm + mi * 16 + lr;
      af[mi] = *(const short8*)(&As[row * ASTR + lk]);
    }
#pragma unroll
    for (int ni = 0; ni < 4; ++ni) {
      int row = wn + ni * 16 + lr;
      bf_[ni] = *(const short8*)(&Bs[buf][row * 32 + (lk ^ (((row >> 1) & 3) << 3))]);
    }
#pragma unroll
    for (int mi = 0; mi < 4; ++mi)
#pragma unroll
      for (int ni = 0; ni < 4; ++ni)
        acc[mi][ni] = __builtin_amdgcn_mfma_f32_16x16x32_bf16(
            af[mi], bf_[ni], acc[mi][ni], 0, 0, 0);
  };

  STAGE_B(0, 0); STAGE_W1(0, 0);
  __syncthreads();
  for (int t = 0; t < 16; ++t) {
    int pb = t & 1;
    if (t < 15) { STAGE_B(pb ^ 1, (t + 1) * 32); STAGE_W1(pb ^ 1, (t + 1) * 32); }
    H1STEP(pb, t * 32);
    __syncthreads();       // h1 chunk visible (also drains staged loads)
    COMPUTE(pb);
    __syncthreads();       // As/Bs reads done -> next overwrite safe
  }

  // epilogue: h2 = relu(acc + b2) -> bf16
#pragma unroll
  for (int ni = 0; ni < 4; ++ni) {
    int col = n0 + wn + ni * 16 + lr;
    float bv = b2[col];
#pragma unroll
    for (int mi = 0; mi < 4; ++mi) {
#pragma unroll
      for (int j = 0; j < 4; ++j) {
        int row = m0 + wm + mi * 16 + hi * 4 + j;
        h2[(size_t)row * 512 + col] = f2bf(fmaxf(acc[mi][ni][j] + bv, 0.0f));
      }
    }
  }
}

// GEMM3 + mixture-CDF transform, fused — R6-EXACT champion (74.6 us measured).
// Block = 128 rows x 640 cols, 16 waves (4Mx4N), wave = 32 rows x 160 cols ->
// acc[2][10] = 80 regs. Double-buffered BK=32 gload_lds staging (2 x 48KB),
// source-side XOR swizzle g(row)=(row>>1)&3. STAGE(next) before COMPUTE(cur).
// Epilogue: four 32-row phases through [32][644] f32 LDS -> fast transform.
#define PSTR 644
#define BUF1 49152
__global__ __launch_bounds__(1024, 4) void gemm3_fused_kernel(
    const short* __restrict__ A,      // h2 bf16 [NROWS][512]
    const short* __restrict__ Bw,     // w3t bf16 [640][512]
    const float* __restrict__ b3c,    // [640]
    const float* __restrict__ x,      // fp32 [NROWS][64]
    float* __restrict__ out) {
  __shared__ __attribute__((aligned(16))) char lds[98304];
  const int tid = threadIdx.x;
  const int m0 = blockIdx.x * 128;
  const int lane = tid & 63, wid = tid >> 6;   // wid 0..15
  const int wr = wid >> 2, wc = wid & 3;       // wr: 32-row group, wc: 160-col group
  const int lr = lane & 15, hi = lane >> 4, lk = hi * 8;

  f32x4 acc[2][10] = {};

  auto STAGE = [&](int bo, int kt) {
#pragma unroll
    for (int base = wid * 64; base < 3072; base += 1024) {
      int c = base + lane;
      char* dst = lds + bo + (size_t)base * 16;   // HW adds lane*16
      if (base < 512) {                           // A chunks [0,512)
        int row = c >> 2;
        int skb = ((c & 3) ^ ((row >> 1) & 3)) << 4;
        const char* ga = (const char*)(A + (size_t)(m0 + row) * 512 + kt) + skb;
        __builtin_amdgcn_global_load_lds(
            (const __attribute__((address_space(1))) void*)ga,
            (__attribute__((address_space(3))) void*)dst, 16, 0, 0);
      } else {                                    // B chunks [512,3072)
        int q = c - 512;
        int row = q >> 2;
        int skb = ((q & 3) ^ ((row >> 1) & 3)) << 4;
        const char* gb = (const char*)(Bw + (size_t)row * 512 + kt) + skb;
        __builtin_amdgcn_global_load_lds(
            (const __attribute__((address_space(1))) void*)gb,
            (__attribute__((address_space(3))) void*)dst, 16, 0, 0);
      }
    }
  };

  auto COMPUTE = [&](int bo) {
    const short* As = (const short*)(lds + bo);
    const short* Bs = (const short*)(lds + bo + 8192);
    short8 af[2];
#pragma unroll
    for (int mi = 0; mi < 2; ++mi) {
      int row = wr * 32 + mi * 16 + lr;
      int k = lk ^ (((row >> 1) & 3) << 3);
      af[mi] = *(const short8*)(&As[row * 32 + k]);
    }
#pragma unroll
    for (int ni = 0; ni < 10; ++ni) {
      int brow = wc * 160 + ni * 16 + lr;
      int k = lk ^ (((brow >> 1) & 3) << 3);
      short8 bf_ = *(const short8*)(&Bs[brow * 32 + k]);
      acc[0][ni] = __builtin_amdgcn_mfma_f32_16x16x32_bf16(af[0], bf_, acc[0][ni], 0, 0, 0);
      acc[1][ni] = __builtin_amdgcn_mfma_f32_16x16x32_bf16(af[1], bf_, acc[1][ni], 0, 0, 0);
    }
  };

  STAGE(0, 0);
  __syncthreads();
  for (int t = 0; t < 16; t += 2) {
    STAGE(BUF1, (t + 1) * 32);
    COMPUTE(0);
    __syncthreads();
    if (t < 14) STAGE(0, (t + 2) * 32);
    COMPUTE(BUF1);
    __syncthreads();
  }

  // ---- fused transform epilogue: four 32-row phases ----
  float* plds = (float*)lds;                 // [32][PSTR] f32 = 82432 B
  float* xo  = out;
  float* ldo = out + (size_t)NROWS * 64;
#pragma unroll
  for (int p = 0; p < 4; ++p) {
    if (p) __syncthreads();
    if (wr == p) {
#pragma unroll
      for (int mi = 0; mi < 2; ++mi) {
#pragma unroll
        for (int ni = 0; ni < 10; ++ni) {
          int col = wc * 160 + ni * 16 + lr;
          float bv = b3c[col];
#pragma unroll
          for (int j = 0; j < 4; ++j)
            plds[(mi * 16 + hi * 4 + j) * PSTR + col] = acc[mi][ni][j] + bv;
        }
      }
    }
    __syncthreads();
    {
      int rl = tid >> 5, j = tid & 31;       // rl 0..31, j 0..31
      const float* p_ = plds + rl * PSTR;
      int grow = m0 + p * 32 + rl;

      float lg[8];
#pragma unroll
      for (int k = 0; k < 8; ++k) lg[k] = p_[64 + k];
      float mx = lg[0];
#pragma unroll
      for (int k = 1; k < 8; ++k) mx = fmaxf(mx, lg[k]);
      float wgt[8], wsum = 0.0f;
#pragma unroll
      for (int k = 0; k < 8; ++k) { wgt[k] = __expf(lg[k] - mx); wsum += wgt[k]; }

      float xd = x[(size_t)grow * 64 + 32 + j];
      float zs = 0.0f, ps = 0.0f;
#pragma unroll
      for (int k = 0; k < 8; ++k) {
        float mu   = p_[96 + k * 32 + j];
        float lstd = p_[352 + k * 32 + j];
        float istd = __expf(-lstd);
        float u = (xd - mu) * istd;
        float x2 = 0.5f * u * u;                 // = (u/sqrt2)^2
        float e  = __expf(-x2);                  // e^{-u^2/2}
        ps += wgt[k] * e * istd;
        // 0.5*erfc(|u|/sqrt2), NR rational approx (rel err < 1.2e-7), shares x2:
        float ax = fabsf(u) * 0.70710678118654752f;
        float t_ = fastrcp(fmaf(0.5f, ax, 1.0f));
        float poly = -1.26551223f + t_*(1.00002368f + t_*(0.37409196f +
                     t_*(0.09678418f + t_*(-0.18628806f + t_*(0.27886807f +
                     t_*(-1.13520398f + t_*(1.48851587f + t_*(-0.82215223f +
                     t_*0.17087277f))))))));
        float erfc_half = 0.5f * t_ * __expf(poly - x2);
        float cdf = (u >= 0.0f) ? 1.0f - erfc_half : erfc_half;
        zs += wgt[k] * cdf;
      }
      float winv = fastrcp(wsum);
      float z  = zs * winv;
      float pm = ps * winv * 0.39894228040143268f;
      float logz = __logf(z), log1mz = __logf(1.0f - z);
      float ls = p_[j], bv = p_[32 + j];
      float outv = (logz - log1mz) * __expf(ls) + bv;
      float ld = __logf(pm) - logz - log1mz + ls;

      size_t base = (size_t)grow * 64;
      xo[base + j]       = x[base + j];
      xo[base + 32 + j]  = outv;
      ldo[base + j]      = 0.0f;
      ldo[base + 32 + j] = ld;
    }
  }
}

extern "C" void kernel_launch(void* const* d_in, const int* in_sizes, int n_in,
                              void* d_out, int out_size, void* d_ws, size_t ws_size,
                              hipStream_t stream) {
  const float* x  = (const float*)d_in[0];
  const float* W1 = (const float*)d_in[1];
  const float* b1 = (const float*)d_in[2];
  const float* W2 = (const float*)d_in[3];
  const float* b2 = (const float*)d_in[4];
  const float* W3 = (const float*)d_in[5];
  const float* b3 = (const float*)d_in[6];
  char* ws = (char*)d_ws;

  short* h2  = (short*)ws;                          // 64 MB  bf16 [65536][512]
  short* w1t = (short*)(ws + 67108864);             // 32 KB  bf16 [512][32]
  short* w2t = (short*)(ws + 67141632);             // 512 KB bf16 [512][512]
  short* w3t = (short*)(ws + 67665920);             // 640 KB bf16 [640][512]
  float* b3c = (float*)(ws + 68321280);             // 2.5 KB fp32 [640]
  float* out = (float*)d_out;

  {
    int total = 512 * 32 + 512 * 512 + NCOMPACT * 512 + NCOMPACT;
    prep_w_kernel<<<(total + 255) / 256, 256, 0, stream>>>(W1, W2, W3, b3, w1t, w2t, w3t, b3c);
  }
  g12_kernel<<<2048, 256, 0, stream>>>(x, w1t, b1, w2t, b2, h2);
  gemm3_fused_kernel<<<NROWS / 128, 1024, 0, stream>>>(h2, w3t, b3c, x, out);
}